// Round 3
// baseline (6067.926 us; speedup 1.0000x reference)
//
#include <hip/hip_runtime.h>
#include <hip/hip_bf16.h>
#include <math.h>

typedef __hip_bfloat16 bf16;

#define B_    16
#define L0_   4096
#define IN_   8
#define D_    256
#define H_    8
#define DK_   32
#define FF_   1024
#define PRED_ 24
#define SCALE_ 0.17677669529663687f   // 1/sqrt(32)

__device__ __forceinline__ float b2f(bf16 v) { return __bfloat162float(v); }
__device__ __forceinline__ bf16  f2b(float v){ return __float2bfloat16(v); }
__device__ __forceinline__ float gelu_exact(float x){
  return 0.5f * x * (1.0f + erff(x * 0.7071067811865476f));
}

// ---------------- dtype detector ----------------
// If x is truly bf16 (values ~N(0,1)), even-index elements have small exponents.
// If x is fp32 read as bf16, even-index elements are float low-halves: random
// exponent bits -> many huge magnitudes. flag=1 means inputs are fp32.
__global__ __launch_bounds__(256) void detect_mode_kernel(
    const unsigned short* __restrict__ x16, int* __restrict__ flag)
{
  int tid = threadIdx.x;
  int cnt = 0;
  for (int i = tid; i < 512; i += 256) {
    unsigned short v = x16[2 * i];
    int expo = (v >> 7) & 0xFF;
    if (expo >= 0x90) cnt++;     // |v| >= 2^17 — impossible for N(0,1) bf16
  }
  __shared__ int red[256];
  red[tid] = cnt;
  __syncthreads();
  for (int s = 128; s > 0; s >>= 1) {
    if (tid < s) red[tid] += red[tid + s];
    __syncthreads();
  }
  if (tid == 0) flag[0] = (red[0] > 8) ? 1 : 0;
}

// ---------------- canonicalize one array to bf16 ----------------
__global__ __launch_bounds__(256) void canon_kernel(
    const void* __restrict__ src, bf16* __restrict__ dst, int n,
    const int* __restrict__ flag)
{
  int i = blockIdx.x * 256 + threadIdx.x;
  if (i >= n) return;
  if (flag[0]) dst[i] = f2b(((const float*)src)[i]);
  else         dst[i] = ((const bf16*)src)[i];
}

// ---------------- embed: h = x@in_w + in_b + pos_emb ----------------
__global__ __launch_bounds__(256) void embed_kernel(
    const bf16* __restrict__ x, const bf16* __restrict__ in_w,
    const bf16* __restrict__ in_b, const bf16* __restrict__ pos,
    bf16* __restrict__ h)
{
  int token = blockIdx.x;          // B*L0
  int d = threadIdx.x;             // 0..255
  int l = token % L0_;
  const bf16* xr = x + (size_t)token * IN_;
  float s = b2f(in_b[d]) + b2f(pos[(size_t)l * D_ + d]);
#pragma unroll
  for (int k = 0; k < IN_; ++k) s += b2f(xr[k]) * b2f(in_w[k * D_ + d]);
  h[(size_t)token * D_ + d] = f2b(s);
}

// ---------------- generic GEMM: C(bf16) = act(A @ W + bias) ----------------
// A: M x K bf16 row-major, W: K x N bf16 row-major. M%64==0, N%64==0, K%16==0.
template<int ACT>
__global__ __launch_bounds__(256) void gemm_kernel(
    const bf16* __restrict__ A, const bf16* __restrict__ W,
    const bf16* __restrict__ bias, bf16* __restrict__ C,
    int M, int N, int K)
{
  __shared__ float As[16][65];   // [k][m]
  __shared__ float Ws[16][65];   // [k][n]
  int bm = blockIdx.y * 64, bn = blockIdx.x * 64;
  int tid = threadIdx.x;
  int tm = (tid >> 4) << 2;
  int tn = (tid & 15) << 2;
  float acc[4][4] = {};

  int i0 = tid * 4;
  int am = i0 >> 4, ak = i0 & 15;     // A tile: 64 x 16
  int wk = i0 >> 6, wn = i0 & 63;     // W tile: 16 x 64
  const bf16* Ap = A + (size_t)(bm + am) * K + ak;
  const bf16* Wp = W + (size_t)wk * N + bn + wn;

  for (int k0 = 0; k0 < K; k0 += 16) {
    float a0 = b2f(Ap[k0 + 0]);
    float a1 = b2f(Ap[k0 + 1]);
    float a2 = b2f(Ap[k0 + 2]);
    float a3 = b2f(Ap[k0 + 3]);
    const bf16* wp = Wp + (size_t)k0 * N;
    float w0 = b2f(wp[0]), w1 = b2f(wp[1]), w2 = b2f(wp[2]), w3 = b2f(wp[3]);
    __syncthreads();
    As[ak + 0][am] = a0; As[ak + 1][am] = a1; As[ak + 2][am] = a2; As[ak + 3][am] = a3;
    Ws[wk][wn + 0] = w0; Ws[wk][wn + 1] = w1; Ws[wk][wn + 2] = w2; Ws[wk][wn + 3] = w3;
    __syncthreads();
#pragma unroll
    for (int kk = 0; kk < 16; ++kk) {
      float av0 = As[kk][tm + 0], av1 = As[kk][tm + 1];
      float av2 = As[kk][tm + 2], av3 = As[kk][tm + 3];
      float wv0 = Ws[kk][tn + 0], wv1 = Ws[kk][tn + 1];
      float wv2 = Ws[kk][tn + 2], wv3 = Ws[kk][tn + 3];
      acc[0][0] += av0 * wv0; acc[0][1] += av0 * wv1; acc[0][2] += av0 * wv2; acc[0][3] += av0 * wv3;
      acc[1][0] += av1 * wv0; acc[1][1] += av1 * wv1; acc[1][2] += av1 * wv2; acc[1][3] += av1 * wv3;
      acc[2][0] += av2 * wv0; acc[2][1] += av2 * wv1; acc[2][2] += av2 * wv2; acc[2][3] += av2 * wv3;
      acc[3][0] += av3 * wv0; acc[3][1] += av3 * wv1; acc[3][2] += av3 * wv2; acc[3][3] += av3 * wv3;
    }
  }
  float bs[4];
#pragma unroll
  for (int j = 0; j < 4; ++j) bs[j] = b2f(bias[bn + tn + j]);
#pragma unroll
  for (int i = 0; i < 4; ++i) {
#pragma unroll
    for (int j = 0; j < 4; ++j) {
      float v = acc[i][j] + bs[j];
      if (ACT == 1) v = gelu_exact(v);
      C[(size_t)(bm + tm + i) * N + bn + tn + j] = f2b(v);
    }
  }
}

// ---------------- ProbSparse M scores ----------------
__global__ __launch_bounds__(256) void prob_scores_kernel(
    const bf16* __restrict__ Q, const bf16* __restrict__ Kc,
    const int* __restrict__ idx, float* __restrict__ Mout, int L, int u)
{
  int g = blockIdx.x * 256 + threadIdx.x;
  if (g >= B_ * H_ * L) return;
  int l = g % L;
  int hh = (g / L) % H_;
  int b = g / (L * H_);
  const bf16* qp = Q + ((size_t)b * L + l) * D_ + hh * DK_;
  float qv[DK_];
#pragma unroll
  for (int j = 0; j < DK_; ++j) qv[j] = b2f(qp[j]);
  float mx = -3.4e38f, sm = 0.f;
  for (int t = 0; t < u; ++t) {
    int ls = idx[t];
    if (ls < 0) ls = 0; if (ls >= L) ls = L - 1;
    const bf16* kp = Kc + ((size_t)b * L + ls) * D_ + hh * DK_;
    float s = 0.f;
#pragma unroll
    for (int j = 0; j < DK_; ++j) s += qv[j] * b2f(kp[j]);
    s *= SCALE_;
    mx = fmaxf(mx, s);
    sm += s;
  }
  Mout[g] = mx - sm / (float)u;
}

// ---------------- deterministic top-k (ties -> lower index), clamped ----------------
__global__ __launch_bounds__(256) void topk_kernel(
    const float* __restrict__ M, int* __restrict__ top, int L, int u)
{
  int bh = blockIdx.x;             // B*H
  __shared__ float mv[L0_];
  __shared__ float rv[256];
  __shared__ int   ri[256];
  int tid = threadIdx.x;
  for (int l = tid; l < L; l += 256) mv[l] = M[(size_t)bh * L + l];
  __syncthreads();
  for (int it = 0; it < u; ++it) {
    float bv = -3.4e38f; int bi = 0;
    for (int l = tid; l < L; l += 256) {
      float v = mv[l];
      if (v > bv || (v == bv && l < bi)) { bv = v; bi = l; }
    }
    rv[tid] = bv; ri[tid] = bi;
    __syncthreads();
    for (int s = 128; s > 0; s >>= 1) {
      if (tid < s) {
        if (rv[tid + s] > rv[tid] || (rv[tid + s] == rv[tid] && ri[tid + s] < ri[tid])) {
          rv[tid] = rv[tid + s]; ri[tid] = ri[tid + s];
        }
      }
      __syncthreads();
    }
    if (tid == 0) {
      int sel = ri[0];
      if (sel < 0) sel = 0; if (sel >= L) sel = L - 1;
      top[bh * u + it] = sel;
      mv[sel] = -3.4e38f;
    }
    __syncthreads();
  }
}

// ---------------- full attention rows for top queries ----------------
__global__ __launch_bounds__(256) void topq_attn_kernel(
    const bf16* __restrict__ Q, const bf16* __restrict__ Kc,
    const bf16* __restrict__ V, const int* __restrict__ top,
    float* __restrict__ ctx_top, int L, int u)
{
  int blk = blockIdx.x;            // (b*H + h)*u + uu
  int uu = blk % u;
  int hh = (blk / u) % H_;
  int b  = blk / (u * H_);
  int lq = top[(b * H_ + hh) * u + uu];
  if (lq < 0) lq = 0; if (lq >= L) lq = L - 1;

  __shared__ float sc[L0_];
  __shared__ float qs[DK_];
  __shared__ float lds4[4];
  __shared__ float wred[4][DK_];
  int tid = threadIdx.x;
  if (tid < DK_) qs[tid] = b2f(Q[((size_t)b * L + lq) * D_ + hh * DK_ + tid]);
  __syncthreads();

  float lmax = -3.4e38f;
  for (int l = tid; l < L; l += 256) {
    const bf16* kp = Kc + ((size_t)b * L + l) * D_ + hh * DK_;
    float s = 0.f;
#pragma unroll
    for (int j = 0; j < DK_; ++j) s += qs[j] * b2f(kp[j]);
    s *= SCALE_;
    sc[l] = s;
    lmax = fmaxf(lmax, s);
  }
  for (int off = 32; off; off >>= 1) lmax = fmaxf(lmax, __shfl_down(lmax, off));
  if ((tid & 63) == 0) lds4[tid >> 6] = lmax;
  __syncthreads();
  float gmax = fmaxf(fmaxf(lds4[0], lds4[1]), fmaxf(lds4[2], lds4[3]));
  __syncthreads();

  float acc[DK_];
#pragma unroll
  for (int j = 0; j < DK_; ++j) acc[j] = 0.f;
  float lsum = 0.f;
  for (int l = tid; l < L; l += 256) {
    float p = expf(sc[l] - gmax);
    lsum += p;
    const bf16* vp = V + ((size_t)b * L + l) * D_ + hh * DK_;
#pragma unroll
    for (int j = 0; j < DK_; ++j) acc[j] += p * b2f(vp[j]);
  }
  for (int off = 32; off; off >>= 1) lsum += __shfl_down(lsum, off);
  if ((tid & 63) == 0) lds4[tid >> 6] = lsum;
#pragma unroll
  for (int j = 0; j < DK_; ++j) {
    float v = acc[j];
    for (int off = 32; off; off >>= 1) v += __shfl_down(v, off);
    acc[j] = v;
  }
  if ((tid & 63) == 0) {
#pragma unroll
    for (int j = 0; j < DK_; ++j) wred[tid >> 6][j] = acc[j];
  }
  __syncthreads();
  if (tid < DK_) {
    float gsum = lds4[0] + lds4[1] + lds4[2] + lds4[3];
    float s = wred[0][tid] + wred[1][tid] + wred[2][tid] + wred[3][tid];
    ctx_top[(size_t)blk * DK_ + tid] = s / gsum;
  }
}

// ---------------- V mean over L ----------------
__global__ __launch_bounds__(256) void vmean_kernel(
    const bf16* __restrict__ V, float* __restrict__ vmean, int L)
{
  int bh = blockIdx.x;
  int b = bh / H_, hh = bh % H_;
  int tid = threadIdx.x;
  __shared__ float wred[4][DK_];
  float acc[DK_];
#pragma unroll
  for (int j = 0; j < DK_; ++j) acc[j] = 0.f;
  for (int l = tid; l < L; l += 256) {
    const bf16* vp = V + ((size_t)b * L + l) * D_ + hh * DK_;
#pragma unroll
    for (int j = 0; j < DK_; ++j) acc[j] += b2f(vp[j]);
  }
#pragma unroll
  for (int j = 0; j < DK_; ++j) {
    float v = acc[j];
    for (int off = 32; off; off >>= 1) v += __shfl_down(v, off);
    acc[j] = v;
  }
  if ((tid & 63) == 0) {
#pragma unroll
    for (int j = 0; j < DK_; ++j) wred[tid >> 6][j] = acc[j];
  }
  __syncthreads();
  if (tid < DK_)
    vmean[bh * DK_ + tid] =
        (wred[0][tid] + wred[1][tid] + wred[2][tid] + wred[3][tid]) / (float)L;
}

// ---------------- ctx = broadcast vmean ----------------
__global__ __launch_bounds__(256) void fill_ctx_kernel(
    const float* __restrict__ vmean, bf16* __restrict__ ctx, int L)
{
  size_t i = (size_t)blockIdx.x * 256 + threadIdx.x;   // < B*L*D
  int d = (int)(i % D_);
  size_t token = i / D_;
  int b = (int)(token / L);
  ctx[i] = f2b(vmean[(b * H_ + d / DK_) * DK_ + (d & (DK_ - 1))]);
}

// ---------------- scatter ctx_top into ctx ----------------
__global__ __launch_bounds__(256) void scatter_kernel(
    const float* __restrict__ ctx_top, const int* __restrict__ top,
    bf16* __restrict__ ctx, int L, int u)
{
  int t = blockIdx.x * 256 + threadIdx.x;
  int total = B_ * H_ * u * DK_;
  if (t >= total) return;
  int j  = t % DK_;
  int uu = (t / DK_) % u;
  int hh = (t / (DK_ * u)) % H_;
  int b  = t / (DK_ * u * H_);
  int lq = top[(b * H_ + hh) * u + uu];
  if (lq < 0) lq = 0; if (lq >= L) lq = L - 1;
  ctx[((size_t)b * L + lq) * D_ + hh * DK_ + j] =
      f2b(ctx_top[(size_t)((b * H_ + hh) * u + uu) * DK_ + j]);
}

// ---------------- h = LayerNorm(h + r) ----------------
__global__ __launch_bounds__(256) void add_ln_kernel(
    bf16* __restrict__ h, const bf16* __restrict__ r,
    const bf16* __restrict__ g, const bf16* __restrict__ be)
{
  size_t t = blockIdx.x;
  int d = threadIdx.x;
  __shared__ float lds4[4];
  float v = b2f(h[t * D_ + d]) + b2f(r[t * D_ + d]);
  float s = v;
  for (int off = 32; off; off >>= 1) s += __shfl_down(s, off);
  if ((threadIdx.x & 63) == 0) lds4[threadIdx.x >> 6] = s;
  __syncthreads();
  float mean = (lds4[0] + lds4[1] + lds4[2] + lds4[3]) * (1.f / D_);
  __syncthreads();
  float dv = v - mean;
  float q = dv * dv;
  for (int off = 32; off; off >>= 1) q += __shfl_down(q, off);
  if ((threadIdx.x & 63) == 0) lds4[threadIdx.x >> 6] = q;
  __syncthreads();
  float var = (lds4[0] + lds4[1] + lds4[2] + lds4[3]) * (1.f / D_);
  h[t * D_ + d] = f2b(dv * rsqrtf(var + 1e-5f) * b2f(g[d]) + b2f(be[d]));
}

// ---------------- distill: conv3(pad1) + ELU + maxpool2 ----------------
__global__ __launch_bounds__(256) void distill_kernel(
    const bf16* __restrict__ h, const bf16* __restrict__ cw,
    const bf16* __restrict__ cb, bf16* __restrict__ out, int L)
{
  const int TL = 8;
  int b  = blockIdx.y;
  int l0 = blockIdx.x * TL;
  int o  = threadIdx.x;
  int p0 = 2 * l0;
  __shared__ float hs[2 * TL + 2][D_];
#pragma unroll
  for (int rr = 0; rr < 2 * TL + 2; ++rr) {
    int row = p0 - 1 + rr;
    float v = 0.f;
    if (row >= 0 && row < L) v = b2f(h[((size_t)b * L + row) * D_ + o]);
    hs[rr][o] = v;
  }
  __syncthreads();
  float acc[2 * TL];
#pragma unroll
  for (int p = 0; p < 2 * TL; ++p) acc[p] = 0.f;
  const bf16* wrow = cw + (size_t)o * D_ * 3;
  for (int c = 0; c < D_; ++c) {
    float w0 = b2f(wrow[c * 3 + 0]);
    float w1 = b2f(wrow[c * 3 + 1]);
    float w2 = b2f(wrow[c * 3 + 2]);
    float hv[2 * TL + 2];
#pragma unroll
    for (int rr = 0; rr < 2 * TL + 2; ++rr) hv[rr] = hs[rr][c];
#pragma unroll
    for (int p = 0; p < 2 * TL; ++p)
      acc[p] += hv[p] * w0 + hv[p + 1] * w1 + hv[p + 2] * w2;
  }
  float bias = b2f(cb[o]);
  int Lh = L / 2;
#pragma unroll
  for (int t = 0; t < TL; ++t) {
    float y0 = acc[2 * t] + bias;
    y0 = y0 > 0.f ? y0 : (expf(y0) - 1.f);
    float y1 = acc[2 * t + 1] + bias;
    y1 = y1 > 0.f ? y1 : (expf(y1) - 1.f);
    out[((size_t)b * Lh + l0 + t) * D_ + o] = f2b(fmaxf(y0, y1));
  }
}

// ---------------- bf16 copy ----------------
__global__ __launch_bounds__(256) void copy_bf16_kernel(
    bf16* __restrict__ dst, const bf16* __restrict__ src, size_t n)
{
  size_t i = (size_t)blockIdx.x * 256 + threadIdx.x;
  if (i < n) dst[i] = src[i];
}

// ---------------- final FC on last token (dtype-branched output) ----------------
__global__ __launch_bounds__(64) void final_fc_kernel(
    const bf16* __restrict__ h, const bf16* __restrict__ fcw,
    const bf16* __restrict__ fcb, void* __restrict__ out, int L,
    const int* __restrict__ flag)
{
  int b = blockIdx.x;
  int p = threadIdx.x;
  if (p >= PRED_) return;
  const bf16* hr = h + ((size_t)b * L + (L - 1)) * D_;
  float s = b2f(fcb[p]);
  for (int d = 0; d < D_; ++d) s += b2f(hr[d]) * b2f(fcw[d * PRED_ + p]);
  if (flag[0]) ((float*)out)[b * PRED_ + p] = s;
  else         ((bf16*)out)[b * PRED_ + p]  = f2b(s);
}

// ---------------- host ----------------
extern "C" void kernel_launch(void* const* d_in, const int* in_sizes, int n_in,
                              void* d_out, int out_size, void* d_ws, size_t ws_size,
                              hipStream_t stream)
{
  // ---- workspace layout (~143 MiB total) ----
  const size_t hsz = (size_t)B_ * L0_ * D_;          // 16,777,216 elements
  char* wsc = (char*)d_ws;
  bf16* h  = (bf16*)wsc;                             // [0, 32M)
  bf16* Qb = (bf16*)(wsc + hsz * 2);                 // [32M, 64M)
  bf16* Kb = (bf16*)(wsc + hsz * 4);                 // [64M, 96M)
  bf16* Vb = (bf16*)(wsc + hsz * 6);                 // [96M, 128M)
  char* misc = wsc + hsz * 8;                        // 128M
  float* Mbuf    = (float*)misc;                              // B*H*L0 fp32
  float* ctx_top = (float*)(misc + (size_t)B_ * H_ * L0_ * 4);
  float* vmean   = ctx_top + (size_t)B_ * H_ * 48 * DK_;
  int*   topbuf  = (int*)(vmean + B_ * H_ * DK_);
  int*   flag    = topbuf + B_ * H_ * 48;
  bf16*  canon   = (bf16*)(flag + 4);                // ~12 MiB of canonical bf16

  bf16* ctxb = Vb;            // alias: V dead after vmean+topq_attn
  bf16* ab   = Qb;            // alias: Q dead after topq_attn
  bf16* t1   = Kb;            // alias: K dead after attention
  bf16* hnext = Kb;           // alias: distill output

  // ---- detect input dtype & canonicalize all float arrays to bf16 ----
  detect_mode_kernel<<<1, 256, 0, stream>>>((const unsigned short*)d_in[0], flag);
  bf16* cp[27];
  size_t off = 0;
  for (int i = 0; i < 27; ++i) {
    if (i >= 1 && i <= 3) { cp[i] = nullptr; continue; }   // idx arrays stay int
    cp[i] = canon + off;
    int n = in_sizes[i];
    canon_kernel<<<(n + 255) / 256, 256, 0, stream>>>(d_in[i], cp[i], n, flag);
    off += (size_t)n;
  }
  const bf16 *cx = cp[0], *cin_w = cp[4], *cin_b = cp[5], *cpos = cp[6];
  const bf16 *cqw = cp[7],  *cqb = cp[8],  *ckw = cp[9],  *ckb = cp[10];
  const bf16 *cvw = cp[11], *cvb = cp[12], *cow = cp[13], *cob = cp[14];
  const bf16 *cf1w = cp[15], *cf1b = cp[16], *cf2w = cp[17], *cf2b = cp[18];
  const bf16 *cn1g = cp[19], *cn1b = cp[20], *cn2g = cp[21], *cn2b = cp[22];
  const bf16 *ccw = cp[23], *ccb = cp[24], *cfcw = cp[25], *cfcb = cp[26];
  const int* idx[3] = {(const int*)d_in[1], (const int*)d_in[2], (const int*)d_in[3]};
  int us[3] = {in_sizes[1], in_sizes[2], in_sizes[3]};

  embed_kernel<<<B_ * L0_, 256, 0, stream>>>(cx, cin_w, cin_b, cpos, h);

  int L = L0_;
  for (int i = 0; i < 3; ++i) {
    int tokens = B_ * L;
    int u = us[i];
    dim3 gDD(D_ / 64, tokens / 64);
    gemm_kernel<0><<<gDD, 256, 0, stream>>>(h, cqw + (size_t)i * D_ * D_, cqb + i * D_, Qb, tokens, D_, D_);
    gemm_kernel<0><<<gDD, 256, 0, stream>>>(h, ckw + (size_t)i * D_ * D_, ckb + i * D_, Kb, tokens, D_, D_);
    gemm_kernel<0><<<gDD, 256, 0, stream>>>(h, cvw + (size_t)i * D_ * D_, cvb + i * D_, Vb, tokens, D_, D_);

    prob_scores_kernel<<<(B_ * H_ * L + 255) / 256, 256, 0, stream>>>(Qb, Kb, idx[i], Mbuf, L, u);
    topk_kernel<<<B_ * H_, 256, 0, stream>>>(Mbuf, topbuf, L, u);
    topq_attn_kernel<<<B_ * H_ * u, 256, 0, stream>>>(Qb, Kb, Vb, topbuf, ctx_top, L, u);
    vmean_kernel<<<B_ * H_, 256, 0, stream>>>(Vb, vmean, L);
    fill_ctx_kernel<<<(unsigned)(((size_t)tokens * D_) / 256), 256, 0, stream>>>(vmean, ctxb, L);
    scatter_kernel<<<(B_ * H_ * u * DK_ + 255) / 256, 256, 0, stream>>>(ctx_top, topbuf, ctxb, L, u);
    gemm_kernel<0><<<gDD, 256, 0, stream>>>(ctxb, cow + (size_t)i * D_ * D_, cob + i * D_, ab, tokens, D_, D_);

    add_ln_kernel<<<tokens, 256, 0, stream>>>(h, ab, cn1g + i * D_, cn1b + i * D_);

    const int CH = 16384;
    for (int c0 = 0; c0 < tokens; c0 += CH) {
      int cm = (tokens - c0 < CH) ? (tokens - c0) : CH;
      dim3 g1(FF_ / 64, cm / 64);
      gemm_kernel<1><<<g1, 256, 0, stream>>>(h + (size_t)c0 * D_, cf1w + (size_t)i * D_ * FF_, cf1b + i * FF_, t1, cm, FF_, D_);
      dim3 g2(D_ / 64, cm / 64);
      gemm_kernel<0><<<g2, 256, 0, stream>>>(t1, cf2w + (size_t)i * FF_ * D_, cf2b + i * D_, ab + (size_t)c0 * D_, cm, D_, FF_);
    }
    add_ln_kernel<<<tokens, 256, 0, stream>>>(h, ab, cn2g + i * D_, cn2b + i * D_);

    if (i < 2) {
      int Lh = L / 2;
      dim3 gd(Lh / 8, B_);
      distill_kernel<<<gd, 256, 0, stream>>>(h, ccw + (size_t)i * D_ * D_ * 3, ccb + i * D_, hnext, L);
      size_t n = (size_t)B_ * Lh * D_;
      copy_bf16_kernel<<<(unsigned)((n + 255) / 256), 256, 0, stream>>>(h, hnext, n);
      L = Lh;
    }
  }
  final_fc_kernel<<<B_, 64, 0, stream>>>(h, cfcw, cfcb, d_out, L, flag);
}

// Round 4
// 2141.574 us; speedup vs baseline: 2.8334x; 2.8334x over previous
//
#include <hip/hip_runtime.h>
#include <hip/hip_bf16.h>
#include <math.h>

typedef __hip_bfloat16 bf16;
typedef __attribute__((ext_vector_type(8))) short short8;
typedef __attribute__((ext_vector_type(4))) float floatx4;

#define B_    16
#define L0_   4096
#define IN_   8
#define D_    256
#define H_    8
#define DK_   32
#define FF_   1024
#define PRED_ 24
#define SCALE_ 0.17677669529663687f   // 1/sqrt(32)

__device__ __forceinline__ float b2f(bf16 v) { return __bfloat162float(v); }
__device__ __forceinline__ bf16  f2b(float v){ return __float2bfloat16(v); }
__device__ __forceinline__ float gelu_exact(float x){
  return 0.5f * x * (1.0f + erff(x * 0.7071067811865476f));
}
__device__ __forceinline__ float eluf(float x){ return x > 0.f ? x : (expf(x) - 1.f); }
// flag-branched load: src is fp32 if flag else bf16
__device__ __forceinline__ float ldf(const void* p, size_t i, int f){
  return f ? ((const float*)p)[i] : b2f(((const bf16*)p)[i]);
}
// async global->LDS 16B: lds dest is wave-uniform base + lane*16
__device__ __forceinline__ void gld16(const void* g, const short* l){
  __builtin_amdgcn_global_load_lds(
      (const __attribute__((address_space(1))) unsigned int*)g,
      (__attribute__((address_space(3))) unsigned int*)l, 16, 0, 0);
}

// ---------------- dtype detector (+ zero scratch init) ----------------
__global__ __launch_bounds__(256) void detect_mode_kernel(
    const unsigned short* __restrict__ x16, int* __restrict__ flag,
    bf16* __restrict__ zbuf)
{
  int tid = threadIdx.x;
  if (tid < 32) zbuf[tid] = f2b(0.f);
  int cnt = 0;
  for (int i = tid; i < 512; i += 256) {
    unsigned short v = x16[2 * i];
    int expo = (v >> 7) & 0xFF;
    if (expo >= 0x90) cnt++;     // |v| >= 2^17 — impossible for N(0,1) bf16
  }
  __shared__ int red[256];
  red[tid] = cnt;
  __syncthreads();
  for (int s = 128; s > 0; s >>= 1) {
    if (tid < s) red[tid] += red[tid + s];
    __syncthreads();
  }
  if (tid == 0) flag[0] = (red[0] > 8) ? 1 : 0;
}

// ---------------- canonicalize one array to bf16 ----------------
__global__ __launch_bounds__(256) void canon_kernel(
    const void* __restrict__ src, bf16* __restrict__ dst, int n,
    const int* __restrict__ flag)
{
  int i = blockIdx.x * 256 + threadIdx.x;
  if (i >= n) return;
  dst[i] = f2b(ldf(src, i, flag[0]));
}

// ---------------- transpose weight [K][N] -> [N][K], per layer (blockIdx.y) ----
__global__ __launch_bounds__(256) void transpose_w_kernel(
    const void* __restrict__ src, bf16* __restrict__ dst, int K, int N,
    const int* __restrict__ flag)
{
  int i = blockIdx.x * 256 + threadIdx.x;
  if (i >= K * N) return;
  size_t off = (size_t)blockIdx.y * K * N;
  int k = i / N, n = i % N;
  dst[off + (size_t)n * K + k] = f2b(ldf(src, off + i, flag[0]));
}

// ---------------- conv weight [o][c][3] -> [t][o][c], per layer ----------------
__global__ __launch_bounds__(256) void transpose_cw_kernel(
    const void* __restrict__ src, bf16* __restrict__ dst,
    const int* __restrict__ flag)
{
  int i = blockIdx.x * 256 + threadIdx.x;
  if (i >= D_ * D_ * 3) return;
  size_t off = (size_t)blockIdx.y * D_ * D_ * 3;
  int o = i / (D_ * 3), c = (i / 3) % D_, t = i % 3;
  dst[off + ((size_t)t * D_ + o) * D_ + c] = f2b(ldf(src, off + i, flag[0]));
}

// ---------------- embed: h = x@in_w + in_b + pos_emb (raw inputs, flag-branched) ----
__global__ __launch_bounds__(256) void embed_kernel(
    const void* __restrict__ x, const void* __restrict__ in_w,
    const void* __restrict__ in_b, const void* __restrict__ pos,
    const int* __restrict__ flag, bf16* __restrict__ h)
{
  int token = blockIdx.x;          // B*L0
  int d = threadIdx.x;             // 0..255
  int l = token % L0_;
  int f = flag[0];
  float s = ldf(in_b, d, f) + ldf(pos, (size_t)l * D_ + d, f);
#pragma unroll
  for (int k = 0; k < IN_; ++k)
    s += ldf(x, (size_t)token * IN_ + k, f) * ldf(in_w, k * D_ + d, f);
  h[(size_t)token * D_ + d] = f2b(s);
}

// ---------------- MFMA GEMM: C(bf16 MxN) = act(A @ Wt^T + bias) ----------------
// A: [M][K] bf16 row-major; Wt: [N][K] bf16 row-major (pre-transposed weight).
// M%128==0, N%128==0, K%32==0. Tile 128x128, BK=32, 4 waves, 4x4 16x16 frags.
template<int ACT>
__global__ __launch_bounds__(256) void mfma_gemm(
    const bf16* __restrict__ A, const bf16* __restrict__ Wt,
    const bf16* __restrict__ bias, bf16* __restrict__ C,
    int M, int N, int K)
{
  __shared__ short As[128 * 32];
  __shared__ short Bs[128 * 32];
  int tid = threadIdx.x;
  int w = tid >> 6, lane = tid & 63;
  int ln = lane & 15, qd = lane >> 4;
  int bm = blockIdx.y << 7, bn = blockIdx.x << 7;
  int wm = (w >> 1) << 6, wn = (w & 1) << 6;

  floatx4 acc[4][4];
#pragma unroll
  for (int mi = 0; mi < 4; ++mi)
#pragma unroll
    for (int ni = 0; ni < 4; ++ni) {
      acc[mi][ni][0] = 0.f; acc[mi][ni][1] = 0.f;
      acc[mi][ni][2] = 0.f; acc[mi][ni][3] = 0.f;
    }

  // staging: 512 chunks of 16B per tile; wave w stages chunks w*128 .. w*128+127
  int s0 = (w << 7) + lane, s1 = s0 + 64;
  int r0 = s0 >> 2, c0 = (s0 & 3) ^ (r0 & 3);   // XOR swizzle of 16B chunks
  int r1 = s1 >> 2, c1 = (s1 & 3) ^ (r1 & 3);
  const bf16* pA0 = A + (size_t)(bm + r0) * K + (c0 << 3);
  const bf16* pA1 = A + (size_t)(bm + r1) * K + (c1 << 3);
  const bf16* pB0 = Wt + (size_t)(bn + r0) * K + (c0 << 3);
  const bf16* pB1 = Wt + (size_t)(bn + r1) * K + (c1 << 3);
  short* ldsA = As + (w << 10);
  short* ldsB = Bs + (w << 10);

  for (int k0 = 0; k0 < K; k0 += 32) {
    __syncthreads();                       // prev iter ds_reads done
    gld16(pA0 + k0, ldsA);
    gld16(pA1 + k0, ldsA + 512);
    gld16(pB0 + k0, ldsB);
    gld16(pB1 + k0, ldsB + 512);
    __syncthreads();                       // drains vmcnt before ds_read
    short8 af[4], bff[4];
#pragma unroll
    for (int mi = 0; mi < 4; ++mi) {
      int r = wm + mi * 16 + ln;
      af[mi] = *(const short8*)(As + (r << 5) + ((qd ^ (r & 3)) << 3));
    }
#pragma unroll
    for (int ni = 0; ni < 4; ++ni) {
      int r = wn + ni * 16 + ln;
      bff[ni] = *(const short8*)(Bs + (r << 5) + ((qd ^ (r & 3)) << 3));
    }
#pragma unroll
    for (int mi = 0; mi < 4; ++mi)
#pragma unroll
      for (int ni = 0; ni < 4; ++ni)
        acc[mi][ni] = __builtin_amdgcn_mfma_f32_16x16x32_bf16(
            af[mi], bff[ni], acc[mi][ni], 0, 0, 0);
  }

#pragma unroll
  for (int ni = 0; ni < 4; ++ni) {
    int col = bn + wn + ni * 16 + ln;
    float bv = b2f(bias[col]);
#pragma unroll
    for (int mi = 0; mi < 4; ++mi) {
      int row = bm + wm + mi * 16 + (qd << 2);
#pragma unroll
      for (int r = 0; r < 4; ++r) {
        float v = acc[mi][ni][r] + bv;
        if (ACT == 1) v = gelu_exact(v);
        C[(size_t)(row + r) * N + col] = f2b(v);
      }
    }
  }
}

// ---------------- MFMA fused conv3(pad1)+bias+ELU+maxpool2 ----------------
// h: [B][L][D] bf16; WtC: [3][D][D] ([tap][o][c]); out: [B][L/2][D] bf16.
// Block: 128 conv positions (within one batch) x 128 out channels.
__global__ __launch_bounds__(256) void mfma_conv_distill(
    const bf16* __restrict__ hsrc, const bf16* __restrict__ WtC,
    const bf16* __restrict__ cb, bf16* __restrict__ outp,
    const bf16* __restrict__ zbuf, int L)
{
  __shared__ short As[128 * 32];
  __shared__ short Bs[128 * 32];
  int tid = threadIdx.x;
  int w = tid >> 6, lane = tid & 63;
  int ln = lane & 15, qd = lane >> 4;
  int bn = blockIdx.x << 7;
  int bpb = L >> 7;                         // blocks per batch
  int b = blockIdx.y / bpb;
  int p0 = (blockIdx.y % bpb) << 7;
  int wm = (w >> 1) << 6, wn = (w & 1) << 6;

  floatx4 acc[4][4];
#pragma unroll
  for (int mi = 0; mi < 4; ++mi)
#pragma unroll
    for (int ni = 0; ni < 4; ++ni) {
      acc[mi][ni][0] = 0.f; acc[mi][ni][1] = 0.f;
      acc[mi][ni][2] = 0.f; acc[mi][ni][3] = 0.f;
    }

  int s0 = (w << 7) + lane, s1 = s0 + 64;
  int r0 = s0 >> 2, c0 = (s0 & 3) ^ (r0 & 3);
  int r1 = s1 >> 2, c1 = (s1 & 3) ^ (r1 & 3);
  short* ldsA = As + (w << 10);
  short* ldsB = Bs + (w << 10);

  for (int tap = 0; tap < 3; ++tap) {
    const bf16* wt = WtC + (size_t)tap * D_ * D_;
    int pos0 = p0 + r0 + tap - 1;
    int pos1 = p0 + r1 + tap - 1;
    const bf16* gA0 = (pos0 >= 0 && pos0 < L)
        ? hsrc + ((size_t)b * L + pos0) * D_ + (c0 << 3) : zbuf;
    const bf16* gA1 = (pos1 >= 0 && pos1 < L)
        ? hsrc + ((size_t)b * L + pos1) * D_ + (c1 << 3) : zbuf;
    int stepA0 = (pos0 >= 0 && pos0 < L) ? 1 : 0;
    int stepA1 = (pos1 >= 0 && pos1 < L) ? 1 : 0;
    const bf16* gB0 = wt + (size_t)(bn + r0) * D_ + (c0 << 3);
    const bf16* gB1 = wt + (size_t)(bn + r1) * D_ + (c1 << 3);
    for (int k0 = 0; k0 < D_; k0 += 32) {
      __syncthreads();
      gld16(gA0 + (size_t)k0 * stepA0, ldsA);
      gld16(gA1 + (size_t)k0 * stepA1, ldsA + 512);
      gld16(gB0 + k0, ldsB);
      gld16(gB1 + k0, ldsB + 512);
      __syncthreads();
      short8 af[4], bff[4];
#pragma unroll
      for (int mi = 0; mi < 4; ++mi) {
        int r = wm + mi * 16 + ln;
        af[mi] = *(const short8*)(As + (r << 5) + ((qd ^ (r & 3)) << 3));
      }
#pragma unroll
      for (int ni = 0; ni < 4; ++ni) {
        int r = wn + ni * 16 + ln;
        bff[ni] = *(const short8*)(Bs + (r << 5) + ((qd ^ (r & 3)) << 3));
      }
#pragma unroll
      for (int mi = 0; mi < 4; ++mi)
#pragma unroll
        for (int ni = 0; ni < 4; ++ni)
          acc[mi][ni] = __builtin_amdgcn_mfma_f32_16x16x32_bf16(
              af[mi], bff[ni], acc[mi][ni], 0, 0, 0);
    }
  }

  int Lh = L >> 1;
#pragma unroll
  for (int ni = 0; ni < 4; ++ni) {
    int col = bn + wn + ni * 16 + ln;
    float bv = b2f(cb[col]);
#pragma unroll
    for (int mi = 0; mi < 4; ++mi) {
      float y0 = eluf(acc[mi][ni][0] + bv);
      float y1 = eluf(acc[mi][ni][1] + bv);
      float y2 = eluf(acc[mi][ni][2] + bv);
      float y3 = eluf(acc[mi][ni][3] + bv);
      int prow = (p0 + wm + mi * 16 + (qd << 2)) >> 1;   // pooled row base (pairs in-lane)
      outp[((size_t)b * Lh + prow) * D_ + col]     = f2b(fmaxf(y0, y1));
      outp[((size_t)b * Lh + prow + 1) * D_ + col] = f2b(fmaxf(y2, y3));
    }
  }
}

// ---------------- ProbSparse M scores ----------------
__global__ __launch_bounds__(256) void prob_scores_kernel(
    const bf16* __restrict__ Q, const bf16* __restrict__ Kc,
    const int* __restrict__ idx, float* __restrict__ Mout, int L, int u)
{
  int g = blockIdx.x * 256 + threadIdx.x;
  if (g >= B_ * H_ * L) return;
  int l = g % L;
  int hh = (g / L) % H_;
  int b = g / (L * H_);
  const bf16* qp = Q + ((size_t)b * L + l) * D_ + hh * DK_;
  float qv[DK_];
#pragma unroll
  for (int j = 0; j < DK_; ++j) qv[j] = b2f(qp[j]);
  float mx = -3.4e38f, sm = 0.f;
  for (int t = 0; t < u; ++t) {
    int ls = idx[t];
    if (ls < 0) ls = 0; if (ls >= L) ls = L - 1;
    const bf16* kp = Kc + ((size_t)b * L + ls) * D_ + hh * DK_;
    float s = 0.f;
#pragma unroll
    for (int j = 0; j < DK_; ++j) s += qv[j] * b2f(kp[j]);
    s *= SCALE_;
    mx = fmaxf(mx, s);
    sm += s;
  }
  Mout[g] = mx - sm / (float)u;
}

// ---------------- deterministic top-k (ties -> lower index), clamped ----------------
__global__ __launch_bounds__(256) void topk_kernel(
    const float* __restrict__ M, int* __restrict__ top, int L, int u)
{
  int bh = blockIdx.x;             // B*H
  __shared__ float mv[L0_];
  __shared__ float rv[256];
  __shared__ int   ri[256];
  int tid = threadIdx.x;
  for (int l = tid; l < L; l += 256) mv[l] = M[(size_t)bh * L + l];
  __syncthreads();
  for (int it = 0; it < u; ++it) {
    float bv = -3.4e38f; int bi = 0;
    for (int l = tid; l < L; l += 256) {
      float v = mv[l];
      if (v > bv || (v == bv && l < bi)) { bv = v; bi = l; }
    }
    rv[tid] = bv; ri[tid] = bi;
    __syncthreads();
    for (int s = 128; s > 0; s >>= 1) {
      if (tid < s) {
        if (rv[tid + s] > rv[tid] || (rv[tid + s] == rv[tid] && ri[tid + s] < ri[tid])) {
          rv[tid] = rv[tid + s]; ri[tid] = ri[tid + s];
        }
      }
      __syncthreads();
    }
    if (tid == 0) {
      int sel = ri[0];
      if (sel < 0) sel = 0; if (sel >= L) sel = L - 1;
      top[bh * u + it] = sel;
      mv[sel] = -3.4e38f;
    }
    __syncthreads();
  }
}

// ---------------- full attention rows for top queries ----------------
__global__ __launch_bounds__(256) void topq_attn_kernel(
    const bf16* __restrict__ Q, const bf16* __restrict__ Kc,
    const bf16* __restrict__ V, const int* __restrict__ top,
    float* __restrict__ ctx_top, int L, int u)
{
  int blk = blockIdx.x;            // (b*H + h)*u + uu
  int uu = blk % u;
  int hh = (blk / u) % H_;
  int b  = blk / (u * H_);
  int lq = top[(b * H_ + hh) * u + uu];
  if (lq < 0) lq = 0; if (lq >= L) lq = L - 1;

  __shared__ float sc[L0_];
  __shared__ float qs[DK_];
  __shared__ float lds4[4];
  __shared__ float wred[4][DK_];
  int tid = threadIdx.x;
  if (tid < DK_) qs[tid] = b2f(Q[((size_t)b * L + lq) * D_ + hh * DK_ + tid]);
  __syncthreads();

  float lmax = -3.4e38f;
  for (int l = tid; l < L; l += 256) {
    const bf16* kp = Kc + ((size_t)b * L + l) * D_ + hh * DK_;
    float s = 0.f;
#pragma unroll
    for (int j = 0; j < DK_; ++j) s += qs[j] * b2f(kp[j]);
    s *= SCALE_;
    sc[l] = s;
    lmax = fmaxf(lmax, s);
  }
  for (int off = 32; off; off >>= 1) lmax = fmaxf(lmax, __shfl_down(lmax, off));
  if ((tid & 63) == 0) lds4[tid >> 6] = lmax;
  __syncthreads();
  float gmax = fmaxf(fmaxf(lds4[0], lds4[1]), fmaxf(lds4[2], lds4[3]));
  __syncthreads();

  float acc[DK_];
#pragma unroll
  for (int j = 0; j < DK_; ++j) acc[j] = 0.f;
  float lsum = 0.f;
  for (int l = tid; l < L; l += 256) {
    float p = expf(sc[l] - gmax);
    lsum += p;
    const bf16* vp = V + ((size_t)b * L + l) * D_ + hh * DK_;
#pragma unroll
    for (int j = 0; j < DK_; ++j) acc[j] += p * b2f(vp[j]);
  }
  for (int off = 32; off; off >>= 1) lsum += __shfl_down(lsum, off);
  if ((tid & 63) == 0) lds4[tid >> 6] = lsum;
#pragma unroll
  for (int j = 0; j < DK_; ++j) {
    float v = acc[j];
    for (int off = 32; off; off >>= 1) v += __shfl_down(v, off);
    acc[j] = v;
  }
  if ((tid & 63) == 0) {
#pragma unroll
    for (int j = 0; j < DK_; ++j) wred[tid >> 6][j] = acc[j];
  }
  __syncthreads();
  if (tid < DK_) {
    float gsum = lds4[0] + lds4[1] + lds4[2] + lds4[3];
    float s = wred[0][tid] + wred[1][tid] + wred[2][tid] + wred[3][tid];
    ctx_top[(size_t)blk * DK_ + tid] = s / gsum;
  }
}

// ---------------- V mean over L ----------------
__global__ __launch_bounds__(256) void vmean_kernel(
    const bf16* __restrict__ V, float* __restrict__ vmean, int L)
{
  int bh = blockIdx.x;
  int b = bh / H_, hh = bh % H_;
  int tid = threadIdx.x;
  __shared__ float wred[4][DK_];
  float acc[DK_];
#pragma unroll
  for (int j = 0; j < DK_; ++j) acc[j] = 0.f;
  for (int l = tid; l < L; l += 256) {
    const bf16* vp = V + ((size_t)b * L + l) * D_ + hh * DK_;
#pragma unroll
    for (int j = 0; j < DK_; ++j) acc[j] += b2f(vp[j]);
  }
#pragma unroll
  for (int j = 0; j < DK_; ++j) {
    float v = acc[j];
    for (int off = 32; off; off >>= 1) v += __shfl_down(v, off);
    acc[j] = v;
  }
  if ((tid & 63) == 0) {
#pragma unroll
    for (int j = 0; j < DK_; ++j) wred[tid >> 6][j] = acc[j];
  }
  __syncthreads();
  if (tid < DK_)
    vmean[bh * DK_ + tid] =
        (wred[0][tid] + wred[1][tid] + wred[2][tid] + wred[3][tid]) / (float)L;
}

// ---------------- ctx = broadcast vmean ----------------
__global__ __launch_bounds__(256) void fill_ctx_kernel(
    const float* __restrict__ vmean, bf16* __restrict__ ctx, int L)
{
  size_t i = (size_t)blockIdx.x * 256 + threadIdx.x;   // < B*L*D
  int d = (int)(i % D_);
  size_t token = i / D_;
  int b = (int)(token / L);
  ctx[i] = f2b(vmean[(b * H_ + d / DK_) * DK_ + (d & (DK_ - 1))]);
}

// ---------------- scatter ctx_top into ctx ----------------
__global__ __launch_bounds__(256) void scatter_kernel(
    const float* __restrict__ ctx_top, const int* __restrict__ top,
    bf16* __restrict__ ctx, int L, int u)
{
  int t = blockIdx.x * 256 + threadIdx.x;
  int total = B_ * H_ * u * DK_;
  if (t >= total) return;
  int j  = t % DK_;
  int uu = (t / DK_) % u;
  int hh = (t / (DK_ * u)) % H_;
  int b  = t / (DK_ * u * H_);
  int lq = top[(b * H_ + hh) * u + uu];
  if (lq < 0) lq = 0; if (lq >= L) lq = L - 1;
  ctx[((size_t)b * L + lq) * D_ + hh * DK_ + j] =
      f2b(ctx_top[(size_t)((b * H_ + hh) * u + uu) * DK_ + j]);
}

// ---------------- h = LayerNorm(h + r) ----------------
__global__ __launch_bounds__(256) void add_ln_kernel(
    bf16* __restrict__ h, const bf16* __restrict__ r,
    const bf16* __restrict__ g, const bf16* __restrict__ be)
{
  size_t t = blockIdx.x;
  int d = threadIdx.x;
  __shared__ float lds4[4];
  float v = b2f(h[t * D_ + d]) + b2f(r[t * D_ + d]);
  float s = v;
  for (int off = 32; off; off >>= 1) s += __shfl_down(s, off);
  if ((threadIdx.x & 63) == 0) lds4[threadIdx.x >> 6] = s;
  __syncthreads();
  float mean = (lds4[0] + lds4[1] + lds4[2] + lds4[3]) * (1.f / D_);
  __syncthreads();
  float dv = v - mean;
  float q = dv * dv;
  for (int off = 32; off; off >>= 1) q += __shfl_down(q, off);
  if ((threadIdx.x & 63) == 0) lds4[threadIdx.x >> 6] = q;
  __syncthreads();
  float var = (lds4[0] + lds4[1] + lds4[2] + lds4[3]) * (1.f / D_);
  h[t * D_ + d] = f2b(dv * rsqrtf(var + 1e-5f) * b2f(g[d]) + b2f(be[d]));
}

// ---------------- bf16 copy ----------------
__global__ __launch_bounds__(256) void copy_bf16_kernel(
    bf16* __restrict__ dst, const bf16* __restrict__ src, size_t n)
{
  size_t i = (size_t)blockIdx.x * 256 + threadIdx.x;
  if (i < n) dst[i] = src[i];
}

// ---------------- final FC on last token (dtype-branched output) ----------------
__global__ __launch_bounds__(64) void final_fc_kernel(
    const bf16* __restrict__ h, const bf16* __restrict__ fcw,
    const bf16* __restrict__ fcb, void* __restrict__ out, int L,
    const int* __restrict__ flag)
{
  int b = blockIdx.x;
  int p = threadIdx.x;
  if (p >= PRED_) return;
  const bf16* hr = h + ((size_t)b * L + (L - 1)) * D_;
  float s = b2f(fcb[p]);
  for (int d = 0; d < D_; ++d) s += b2f(hr[d]) * b2f(fcw[d * PRED_ + p]);
  if (flag[0]) ((float*)out)[b * PRED_ + p] = s;
  else         ((bf16*)out)[b * PRED_ + p]  = f2b(s);
}

// ---------------- host ----------------
extern "C" void kernel_launch(void* const* d_in, const int* in_sizes, int n_in,
                              void* d_out, int out_size, void* d_ws, size_t ws_size,
                              hipStream_t stream)
{
  const size_t hsz = (size_t)B_ * L0_ * D_;          // 16,777,216 elements
  char* wsc = (char*)d_ws;
  bf16* h  = (bf16*)wsc;
  bf16* Qb = (bf16*)(wsc + hsz * 2);
  bf16* Kb = (bf16*)(wsc + hsz * 4);
  bf16* Vb = (bf16*)(wsc + hsz * 6);
  char* misc = wsc + hsz * 8;
  float* Mbuf    = (float*)misc;                       // B*H*L0 fp32
  float* ctx_top = Mbuf + (size_t)B_ * H_ * L0_;       // B*H*48*DK
  float* vmean   = ctx_top + (size_t)B_ * H_ * 48 * DK_;
  int*   topbuf  = (int*)(vmean + B_ * H_ * DK_);      // B*H*48
  int*   flag    = topbuf + B_ * H_ * 48;
  bf16*  zbuf    = (bf16*)(flag + 4);                  // 32 el zero scratch
  bf16*  canon   = zbuf + 32;                          // transposed weights + small arrays

  // transposed-weight layout in canon
  bf16* qwT  = canon;                       // 3 * 256*256
  bf16* kwT  = qwT  + 3 * 65536;
  bf16* vwT  = kwT  + 3 * 65536;
  bf16* owT  = vwT  + 3 * 65536;
  bf16* f1wT = owT  + 3 * 65536;            // 3 * 1024*256  ([FF][D] per layer)
  bf16* f2wT = f1wT + 3 * 262144;           // 3 * 256*1024  ([D][FF] per layer)
  bf16* cwT  = f2wT + 3 * 262144;           // 2 * 3*256*256 ([t][o][c] per layer)
  bf16* smallc = cwT + 2 * 196608;

  bf16* ctxb = Vb;            // alias: V dead after vmean+topq_attn
  bf16* ab   = Qb;            // alias: Q dead after topq_attn
  bf16* t1   = Kb;            // alias: K dead after attention (FFN mid)
  bf16* hnext = Kb;           // alias: distill output

  detect_mode_kernel<<<1, 256, 0, stream>>>((const unsigned short*)d_in[0], flag, zbuf);

  // canonicalize small arrays (biases, LN params, fc)
  const int cidx[13] = {8, 10, 12, 14, 16, 18, 19, 20, 21, 22, 24, 25, 26};
  bf16* cptr[27] = {};
  {
    bf16* p = smallc;
    for (int t = 0; t < 13; ++t) {
      int i = cidx[t];
      int n = in_sizes[i];
      cptr[i] = p;
      canon_kernel<<<(n + 255) / 256, 256, 0, stream>>>(d_in[i], p, n, flag);
      p += (n + 7) & ~7;
    }
  }
  // transpose weights
  transpose_w_kernel<<<dim3(256, 3), 256, 0, stream>>>(d_in[7],  qwT,  256, 256, flag);
  transpose_w_kernel<<<dim3(256, 3), 256, 0, stream>>>(d_in[9],  kwT,  256, 256, flag);
  transpose_w_kernel<<<dim3(256, 3), 256, 0, stream>>>(d_in[11], vwT,  256, 256, flag);
  transpose_w_kernel<<<dim3(256, 3), 256, 0, stream>>>(d_in[13], owT,  256, 256, flag);
  transpose_w_kernel<<<dim3(1024, 3), 256, 0, stream>>>(d_in[15], f1wT, 256, 1024, flag);
  transpose_w_kernel<<<dim3(1024, 3), 256, 0, stream>>>(d_in[17], f2wT, 1024, 256, flag);
  transpose_cw_kernel<<<dim3(768, 2), 256, 0, stream>>>(d_in[23], cwT, flag);

  const int* idx[3] = {(const int*)d_in[1], (const int*)d_in[2], (const int*)d_in[3]};
  int us[3] = {in_sizes[1], in_sizes[2], in_sizes[3]};

  embed_kernel<<<B_ * L0_, 256, 0, stream>>>(d_in[0], d_in[4], d_in[5], d_in[6], flag, h);

  int L = L0_;
  for (int i = 0; i < 3; ++i) {
    int tokens = B_ * L;
    int u = us[i];
    dim3 gDD(2, tokens / 128);
    mfma_gemm<0><<<gDD, 256, 0, stream>>>(h, qwT + (size_t)i * 65536, cptr[8]  + i * D_, Qb, tokens, D_, D_);
    mfma_gemm<0><<<gDD, 256, 0, stream>>>(h, kwT + (size_t)i * 65536, cptr[10] + i * D_, Kb, tokens, D_, D_);
    mfma_gemm<0><<<gDD, 256, 0, stream>>>(h, vwT + (size_t)i * 65536, cptr[12] + i * D_, Vb, tokens, D_, D_);

    prob_scores_kernel<<<(B_ * H_ * L + 255) / 256, 256, 0, stream>>>(Qb, Kb, idx[i], Mbuf, L, u);
    topk_kernel<<<B_ * H_, 256, 0, stream>>>(Mbuf, topbuf, L, u);
    topq_attn_kernel<<<B_ * H_ * u, 256, 0, stream>>>(Qb, Kb, Vb, topbuf, ctx_top, L, u);
    vmean_kernel<<<B_ * H_, 256, 0, stream>>>(Vb, vmean, L);
    fill_ctx_kernel<<<(unsigned)(((size_t)tokens * D_) / 256), 256, 0, stream>>>(vmean, ctxb, L);
    scatter_kernel<<<(B_ * H_ * u * DK_ + 255) / 256, 256, 0, stream>>>(ctx_top, topbuf, ctxb, L, u);
    mfma_gemm<0><<<gDD, 256, 0, stream>>>(ctxb, owT + (size_t)i * 65536, cptr[14] + i * D_, ab, tokens, D_, D_);

    add_ln_kernel<<<tokens, 256, 0, stream>>>(h, ab, cptr[19] + i * D_, cptr[20] + i * D_);

    const int CH = 16384;
    for (int c0 = 0; c0 < tokens; c0 += CH) {
      int cm = (tokens - c0 < CH) ? (tokens - c0) : CH;
      mfma_gemm<1><<<dim3(8, cm / 128), 256, 0, stream>>>(
          h + (size_t)c0 * D_, f1wT + (size_t)i * 262144, cptr[16] + i * FF_, t1, cm, FF_, D_);
      mfma_gemm<0><<<dim3(2, cm / 128), 256, 0, stream>>>(
          t1, f2wT + (size_t)i * 262144, cptr[18] + i * D_, ab + (size_t)c0 * D_, cm, D_, FF_);
    }
    add_ln_kernel<<<tokens, 256, 0, stream>>>(h, ab, cptr[21] + i * D_, cptr[22] + i * D_);

    if (i < 2) {
      int Lh = L / 2;
      mfma_conv_distill<<<dim3(2, B_ * (L / 128)), 256, 0, stream>>>(
          h, cwT + (size_t)i * 196608, cptr[24] + i * D_, hnext, zbuf, L);
      size_t n = (size_t)B_ * Lh * D_;
      copy_bf16_kernel<<<(unsigned)((n + 255) / 256), 256, 0, stream>>>(h, hnext, n);
      L = Lh;
    }
  }
  final_fc_kernel<<<B_, 64, 0, stream>>>(h, cptr[25], cptr[26], d_out, L, flag);
}